// Round 1
// baseline (10099.805 us; speedup 1.0000x reference)
//
#include <hip/hip_runtime.h>
#include <math.h>

#define BATCH 2
#define T 1024
#define CDIM 1024
#define NHEAD 16
#define NLAYER 6
#define VOCAB 32000
#define DHEAD 64
#define EPS 1e-5f

// ---------------------------------------------------------------------------
// Embedding: x[b,t,:] = tok_emb[idx[b,t],:] + pos_emb[t,:]
// ---------------------------------------------------------------------------
__global__ void embed_kernel(const int* __restrict__ idx,
                             const float* __restrict__ tok,
                             const float* __restrict__ pos,
                             float* __restrict__ x) {
    int row = blockIdx.x;              // b*T + t
    int t = row % T;
    int tok_id = idx[row];
    const float4* tp = (const float4*)(tok + (size_t)tok_id * CDIM);
    const float4* pp = (const float4*)(pos + (size_t)t * CDIM);
    float4* xp = (float4*)(x + (size_t)row * CDIM);
    int i = threadIdx.x;               // 256 threads * 4 floats = 1024 = C
    float4 a = tp[i], b4 = pp[i];
    xp[i] = make_float4(a.x + b4.x, a.y + b4.y, a.z + b4.z, a.w + b4.w);
}

// ---------------------------------------------------------------------------
// LayerNorm over last dim (C=1024), one block (256 thr) per row
// ---------------------------------------------------------------------------
__global__ void ln_kernel(const float* __restrict__ in,
                          const float* __restrict__ gamma,
                          const float* __restrict__ beta,
                          float* __restrict__ out) {
    int row = blockIdx.x;
    int i = threadIdx.x;
    const float4* ip = (const float4*)(in + (size_t)row * CDIM);
    float4 v = ip[i];
    float s  = v.x + v.y + v.z + v.w;
    float ss = v.x * v.x + v.y * v.y + v.z * v.z + v.w * v.w;
    #pragma unroll
    for (int off = 32; off > 0; off >>= 1) {
        s  += __shfl_down(s, off);
        ss += __shfl_down(ss, off);
    }
    __shared__ float red[8];
    __shared__ float mu_s, rstd_s;
    int wid = i >> 6, lane = i & 63;
    if (lane == 0) { red[wid] = s; red[wid + 4] = ss; }
    __syncthreads();
    if (i == 0) {
        float S  = red[0] + red[1] + red[2] + red[3];
        float SS = red[4] + red[5] + red[6] + red[7];
        float mu = S / (float)CDIM;
        float var = SS / (float)CDIM - mu * mu;
        mu_s = mu;
        rstd_s = rsqrtf(var + EPS);
    }
    __syncthreads();
    float mu = mu_s, rstd = rstd_s;
    float4 gv = ((const float4*)gamma)[i];
    float4 bv = ((const float4*)beta)[i];
    float4 o;
    o.x = (v.x - mu) * rstd * gv.x + bv.x;
    o.y = (v.y - mu) * rstd * gv.y + bv.y;
    o.z = (v.z - mu) * rstd * gv.z + bv.z;
    o.w = (v.w - mu) * rstd * gv.w + bv.w;
    ((float4*)(out + (size_t)row * CDIM))[i] = o;
}

// ---------------------------------------------------------------------------
// FP32 GEMM: out[M,N] = A[M,K] @ W[K,N] + bias (+res) (relu)
// BM=BN=128, BK=16, 256 threads, 8x8 micro-tile per thread.
// Requires M%128==0, N%128==0, K%16==0 (true for all shapes here).
// ---------------------------------------------------------------------------
template<bool RELU, bool RES>
__global__ __launch_bounds__(256)
void gemm_kernel(const float* __restrict__ A, const float* __restrict__ W,
                 const float* __restrict__ bias, const float* __restrict__ res,
                 float* __restrict__ out, int K, int N) {
    __shared__ float As[16][132];   // [k][m], padded to 132 (16B-aligned rows)
    __shared__ float Bs[16][128];   // [k][n]
    int tid = threadIdx.x;
    int tm = tid >> 4, tn = tid & 15;
    int bm = blockIdx.y, bn = blockIdx.x;

    float acc[8][8] = {};

    const float* Ab = A + (size_t)bm * 128 * K;
    const float* Wb = W + (size_t)bn * 128;

    int arow = tid >> 2;          // 0..63 (two iters: +64)
    int ak   = (tid & 3) * 4;     // 0,4,8,12
    int bk   = tid >> 4;          // 0..15
    int bf   = (tid & 15) * 4;    // 0..60 (two iters: +64)

    for (int kt = 0; kt < K; kt += 16) {
        #pragma unroll
        for (int r = 0; r < 2; ++r) {
            int row = arow + r * 64;
            float4 av = *(const float4*)(Ab + (size_t)row * K + kt + ak);
            As[ak + 0][row] = av.x;
            As[ak + 1][row] = av.y;
            As[ak + 2][row] = av.z;
            As[ak + 3][row] = av.w;
        }
        #pragma unroll
        for (int r = 0; r < 2; ++r) {
            int col = bf + r * 64;
            *(float4*)&Bs[bk][col] = *(const float4*)(Wb + (size_t)(kt + bk) * N + col);
        }
        __syncthreads();
        #pragma unroll
        for (int k = 0; k < 16; ++k) {
            float4 a0 = *(const float4*)&As[k][tm * 8];
            float4 a1 = *(const float4*)&As[k][tm * 8 + 4];
            float4 b0 = *(const float4*)&Bs[k][tn * 8];
            float4 b1 = *(const float4*)&Bs[k][tn * 8 + 4];
            float a[8]  = {a0.x, a0.y, a0.z, a0.w, a1.x, a1.y, a1.z, a1.w};
            float bb[8] = {b0.x, b0.y, b0.z, b0.w, b1.x, b1.y, b1.z, b1.w};
            #pragma unroll
            for (int ii = 0; ii < 8; ++ii)
                #pragma unroll
                for (int jj = 0; jj < 8; ++jj)
                    acc[ii][jj] += a[ii] * bb[jj];
        }
        __syncthreads();
    }

    int orow0 = bm * 128 + tm * 8;
    int ocol0 = bn * 128 + tn * 8;
    #pragma unroll
    for (int ii = 0; ii < 8; ++ii) {
        size_t base = (size_t)(orow0 + ii) * N + ocol0;
        #pragma unroll
        for (int jj = 0; jj < 8; ++jj) {
            float v = acc[ii][jj] + bias[ocol0 + jj];
            if (RES) v += res[base + jj];
            if (RELU) v = fmaxf(v, 0.f);
            out[base + jj] = v;
        }
    }
}

// ---------------------------------------------------------------------------
// Fused causal attention (flash-style). Grid: (T/32, H, B), 256 threads.
// qkv layout per row (B*T rows of 3*C): [q(H,D) | k(H,D) | v(H,D)]
// y layout: [B,T,C] with C = (H,D)
// Thread t: owns q-row rq = t/8; within 8-group: score quad sq=(t%8)*4,
// output d-segment d0=(t%8)*8.
// ---------------------------------------------------------------------------
__global__ __launch_bounds__(256)
void attn_kernel(const float* __restrict__ qkv, float* __restrict__ y) {
    int qt = blockIdx.x;   // q tile (32 rows)
    int h  = blockIdx.y;
    int b  = blockIdx.z;
    __shared__ float Qs[32][68], Ks[32][68], Vs[32][68];
    __shared__ float Ps[32][32];
    int tid = threadIdx.x;
    const size_t rowstride = 3 * CDIM;
    const float* qbase = qkv + (size_t)b * T * rowstride + h * DHEAD;
    const float* kbase = qbase + CDIM;
    const float* vbase = qbase + 2 * CDIM;

    #pragma unroll
    for (int it = 0; it < 2; ++it) {
        int f = tid + it * 256;
        int r = f >> 4, d4 = (f & 15) * 4;
        *(float4*)&Qs[r][d4] =
            *(const float4*)(qbase + (size_t)(qt * 32 + r) * rowstride + d4);
    }

    int rq = tid >> 3;     // 0..31
    int g8 = tid & 7;
    int sq = g8 * 4;
    int d0 = g8 * 8;
    float O[8] = {0, 0, 0, 0, 0, 0, 0, 0};
    float m = -INFINITY, l = 0.f;
    const float scale = 0.125f;   // 1/sqrt(64)

    for (int st = 0; st <= qt; ++st) {
        __syncthreads();   // protect Ks/Vs reuse (and initial Qs visibility)
        #pragma unroll
        for (int it = 0; it < 2; ++it) {
            int f = tid + it * 256;
            int r = f >> 4, d4 = (f & 15) * 4;
            size_t grow = (size_t)(st * 32 + r) * rowstride + d4;
            *(float4*)&Ks[r][d4] = *(const float4*)(kbase + grow);
            *(float4*)&Vs[r][d4] = *(const float4*)(vbase + grow);
        }
        __syncthreads();

        float sc[4] = {0, 0, 0, 0};
        #pragma unroll 8
        for (int d = 0; d < DHEAD; ++d) {
            float qv = Qs[rq][d];
            #pragma unroll
            for (int j = 0; j < 4; ++j) sc[j] += qv * Ks[sq + j][d];
        }
        int qglob = qt * 32 + rq;
        #pragma unroll
        for (int j = 0; j < 4; ++j) {
            int sglob = st * 32 + sq + j;
            sc[j] = (sglob <= qglob) ? sc[j] * scale : -INFINITY;
        }
        float tmax = fmaxf(fmaxf(sc[0], sc[1]), fmaxf(sc[2], sc[3]));
        #pragma unroll
        for (int off = 1; off < 8; off <<= 1)
            tmax = fmaxf(tmax, __shfl_xor(tmax, off, 8));
        float mnew = fmaxf(m, tmax);
        float alpha = expf(m - mnew);   // first tile: exp(-inf)=0
        float p[4];
        float psum = 0.f;
        #pragma unroll
        for (int j = 0; j < 4; ++j) { p[j] = expf(sc[j] - mnew); psum += p[j]; }
        #pragma unroll
        for (int off = 1; off < 8; off <<= 1)
            psum += __shfl_xor(psum, off, 8);
        l = l * alpha + psum;
        m = mnew;
        #pragma unroll
        for (int j = 0; j < 8; ++j) O[j] *= alpha;
        *(float4*)&Ps[rq][sq] = make_float4(p[0], p[1], p[2], p[3]);
        __syncthreads();

        #pragma unroll 4
        for (int s = 0; s < 32; ++s) {
            float pv = Ps[rq][s];
            float4 v0 = *(const float4*)&Vs[s][d0];
            float4 v1 = *(const float4*)&Vs[s][d0 + 4];
            O[0] += pv * v0.x; O[1] += pv * v0.y; O[2] += pv * v0.z; O[3] += pv * v0.w;
            O[4] += pv * v1.x; O[5] += pv * v1.y; O[6] += pv * v1.z; O[7] += pv * v1.w;
        }
    }
    float inv = 1.f / l;
    float* yrow = y + ((size_t)b * T + qt * 32 + rq) * CDIM + h * DHEAD + d0;
    *(float4*)(yrow)     = make_float4(O[0]*inv, O[1]*inv, O[2]*inv, O[3]*inv);
    *(float4*)(yrow + 4) = make_float4(O[4]*inv, O[5]*inv, O[6]*inv, O[7]*inv);
}

// ---------------------------------------------------------------------------
extern "C" void kernel_launch(void* const* d_in, const int* in_sizes, int n_in,
                              void* d_out, int out_size, void* d_ws, size_t ws_size,
                              hipStream_t stream) {
    const int*   idx     = (const int*)d_in[0];
    const float* tok_emb = (const float*)d_in[1];
    const float* pos_emb = (const float*)d_in[2];
    const float* Wqkv    = (const float*)d_in[3];
    const float* bqkv    = (const float*)d_in[4];
    const float* Wproj   = (const float*)d_in[5];
    const float* bproj   = (const float*)d_in[6];
    const float* ln1_g   = (const float*)d_in[7];
    const float* ln1_b   = (const float*)d_in[8];
    const float* ln2_g   = (const float*)d_in[9];
    const float* ln2_b   = (const float*)d_in[10];
    const float* Wf1     = (const float*)d_in[11];
    const float* bf1     = (const float*)d_in[12];
    const float* Wf2     = (const float*)d_in[13];
    const float* bf2     = (const float*)d_in[14];
    const float* lnf_g   = (const float*)d_in[15];
    const float* lnf_b   = (const float*)d_in[16];
    const float* Whead   = (const float*)d_in[17];
    const float* bhead   = (const float*)d_in[18];
    float* out = (float*)d_out;
    float* ws  = (float*)d_ws;

    // workspace layout (floats): x[2M] | h[2M] | buf2[8M] | y[2M]  = 56 MB
    float* x    = ws;
    float* h    = ws + (size_t)2 * 1024 * 1024;
    float* buf2 = ws + (size_t)4 * 1024 * 1024;
    float* y    = ws + (size_t)12 * 1024 * 1024;

    const int MROWS = BATCH * T;  // 2048

    embed_kernel<<<MROWS, 256, 0, stream>>>(idx, tok_emb, pos_emb, x);

    for (int l = 0; l < NLAYER; ++l) {
        ln_kernel<<<MROWS, 256, 0, stream>>>(x, ln1_g + (size_t)l * CDIM,
                                             ln1_b + (size_t)l * CDIM, h);
        gemm_kernel<false, false><<<dim3(24, 16), 256, 0, stream>>>(
            h, Wqkv + (size_t)l * CDIM * 3 * CDIM, bqkv + (size_t)l * 3 * CDIM,
            nullptr, buf2, CDIM, 3 * CDIM);
        attn_kernel<<<dim3(T / 32, NHEAD, BATCH), 256, 0, stream>>>(buf2, y);
        gemm_kernel<false, true><<<dim3(8, 16), 256, 0, stream>>>(
            y, Wproj + (size_t)l * CDIM * CDIM, bproj + (size_t)l * CDIM,
            x, x, CDIM, CDIM);
        ln_kernel<<<MROWS, 256, 0, stream>>>(x, ln2_g + (size_t)l * CDIM,
                                             ln2_b + (size_t)l * CDIM, h);
        gemm_kernel<true, false><<<dim3(32, 16), 256, 0, stream>>>(
            h, Wf1 + (size_t)l * CDIM * 4 * CDIM, bf1 + (size_t)l * 4 * CDIM,
            nullptr, buf2, CDIM, 4 * CDIM);
        gemm_kernel<false, true><<<dim3(8, 16), 256, 0, stream>>>(
            buf2, Wf2 + (size_t)l * 4 * CDIM * CDIM, bf2 + (size_t)l * CDIM,
            x, x, 4 * CDIM, CDIM);
    }

    ln_kernel<<<MROWS, 256, 0, stream>>>(x, lnf_g, lnf_b, h);
    gemm_kernel<false, false><<<dim3(250, 16), 256, 0, stream>>>(
        h, Whead, bhead, nullptr, out, CDIM, VOCAB);
}

// Round 4
// 3340.784 us; speedup vs baseline: 3.0232x; 3.0232x over previous
//
#include <hip/hip_runtime.h>
#include <math.h>

#define BATCH 2
#define T 1024
#define CDIM 1024
#define NHEAD 16
#define NLAYER 6
#define VOCAB 32000
#define DHEAD 64
#define EPS 1e-5f

typedef short s16x8 __attribute__((ext_vector_type(8)));
typedef float f32x4 __attribute__((ext_vector_type(4)));

typedef unsigned int u32_g __attribute__((address_space(1)));
typedef unsigned int u32_l __attribute__((address_space(3)));

__device__ __forceinline__ float bf2f(unsigned short u) {
    return __uint_as_float(((unsigned)u) << 16);
}
__device__ __forceinline__ unsigned short f2bf(float f) {
    unsigned b = __float_as_uint(f);
    b += 0x7FFFu + ((b >> 16) & 1u);
    return (unsigned short)(b >> 16);
}

// ---------------------------------------------------------------------------
// Embedding (fp32 out): x[b,t,:] = tok_emb[idx[b,t],:] + pos_emb[t,:]
// ---------------------------------------------------------------------------
__global__ void embed_kernel(const int* __restrict__ idx,
                             const float* __restrict__ tok,
                             const float* __restrict__ pos,
                             float* __restrict__ x) {
    int row = blockIdx.x;
    int t = row % T;
    int tok_id = idx[row];
    const float4* tp = (const float4*)(tok + (size_t)tok_id * CDIM);
    const float4* pp = (const float4*)(pos + (size_t)t * CDIM);
    float4* xp = (float4*)(x + (size_t)row * CDIM);
    int i = threadIdx.x;
    float4 a = tp[i], b4 = pp[i];
    xp[i] = make_float4(a.x + b4.x, a.y + b4.y, a.z + b4.z, a.w + b4.w);
}

// ---------------------------------------------------------------------------
// LayerNorm fp32 in -> bf16 out. One block (256 thr) per row.
// ---------------------------------------------------------------------------
__global__ void ln_kernel(const float* __restrict__ in,
                          const float* __restrict__ gamma,
                          const float* __restrict__ beta,
                          unsigned short* __restrict__ out) {
    int row = blockIdx.x;
    int i = threadIdx.x;
    float4 v = ((const float4*)(in + (size_t)row * CDIM))[i];
    float s  = v.x + v.y + v.z + v.w;
    float ss = v.x * v.x + v.y * v.y + v.z * v.z + v.w * v.w;
    #pragma unroll
    for (int off = 32; off > 0; off >>= 1) {
        s  += __shfl_down(s, off);
        ss += __shfl_down(ss, off);
    }
    __shared__ float red[8];
    __shared__ float mu_s, rstd_s;
    int wid = i >> 6, lane = i & 63;
    if (lane == 0) { red[wid] = s; red[wid + 4] = ss; }
    __syncthreads();
    if (i == 0) {
        float S  = red[0] + red[1] + red[2] + red[3];
        float SS = red[4] + red[5] + red[6] + red[7];
        float mu = S / (float)CDIM;
        float var = SS / (float)CDIM - mu * mu;
        mu_s = mu;
        rstd_s = rsqrtf(var + EPS);
    }
    __syncthreads();
    float mu = mu_s, rstd = rstd_s;
    float4 gv = ((const float4*)gamma)[i];
    float4 bv = ((const float4*)beta)[i];
    unsigned short o0 = f2bf((v.x - mu) * rstd * gv.x + bv.x);
    unsigned short o1 = f2bf((v.y - mu) * rstd * gv.y + bv.y);
    unsigned short o2 = f2bf((v.z - mu) * rstd * gv.z + bv.z);
    unsigned short o3 = f2bf((v.w - mu) * rstd * gv.w + bv.w);
    uint2 pk;
    pk.x = (unsigned)o0 | ((unsigned)o1 << 16);
    pk.y = (unsigned)o2 | ((unsigned)o3 << 16);
    *(uint2*)(out + (size_t)row * CDIM + i * 4) = pk;
}

// ---------------------------------------------------------------------------
// Weight transpose + fp32->bf16: W[k][n] (ldW) -> WT[n][k] (row stride K)
// grid: (Ncols/64, K/64), 256 threads.
// ---------------------------------------------------------------------------
__global__ __launch_bounds__(256)
void transpose_cvt(const float* __restrict__ W, int ldW,
                   unsigned short* __restrict__ WT, int K) {
    int n  = blockIdx.x * 64 + (threadIdx.x >> 2);
    int k0 = blockIdx.y * 64 + (threadIdx.x & 3) * 16;
    unsigned short tmp[16];
    #pragma unroll
    for (int i = 0; i < 16; ++i)
        tmp[i] = f2bf(W[(size_t)(k0 + i) * ldW + n]);
    *(uint4*)(WT + (size_t)n * K + k0)     = *(uint4*)tmp;
    *(uint4*)(WT + (size_t)n * K + k0 + 8) = *(uint4*)(tmp + 8);
}

// ---------------------------------------------------------------------------
// bf16 MFMA GEMM: out[2048,ldo] = A[2048,K](bf16) @ WT[N,K]^T (bf16) + bias
// MF=4: 128x128 tile; MF=2: 64x128 tile. BK=32, 256 threads (4 waves 2x2).
// LDS tiles [rows][32] bf16 with 16B-chunk XOR swizzle c^((r>>1)&3):
// conflict-free ds_read_b128 frags AND linear global_load_lds dest
// (swizzle applied on the global source address, G21 both-sides rule).
// ---------------------------------------------------------------------------
template<int MF, int MTB, bool OUTBF, bool RES, bool RELU>
__global__ __launch_bounds__(256)
void mfma_gemm(const unsigned short* __restrict__ A,
               const unsigned short* __restrict__ WT,
               const float* __restrict__ bias,
               const float* __restrict__ res,
               void* __restrict__ outp,
               int K, int ldo) {
    constexpr int BM = MF * 32;
    __shared__ __align__(16) short As[BM * 32];
    __shared__ __align__(16) short Bs[128 * 32];
    const int tid  = threadIdx.x;
    const int lane = tid & 63;
    const int w    = tid >> 6;
    const int wm   = w & 1, wn = w >> 1;
    const int bm   = blockIdx.x & ((1 << MTB) - 1);
    const int bn   = blockIdx.x >> MTB;
    const int kc   = lane >> 4;
    const int lr   = lane & 15;

    // LDS frag read offsets (elements), loop-invariant
    int aoff[MF], boff[4];
    #pragma unroll
    for (int m = 0; m < MF; ++m) {
        int r = wm * (BM / 2) + m * 16 + lr;
        aoff[m] = r * 32 + ((kc ^ ((r >> 1) & 3)) * 8);
    }
    #pragma unroll
    for (int n = 0; n < 4; ++n) {
        int r = wn * 64 + n * 16 + lr;
        boff[n] = r * 32 + ((kc ^ ((r >> 1) & 3)) * 8);
    }

    // staging assignments: dest byte d -> row r = d>>6, stored chunk c' = (d>>4)&3,
    // global chunk c = c' ^ ((r>>1)&3)  (involution)
    constexpr int AJ = MF / 2;
    int a_r[AJ], a_c[AJ], a_dst[AJ];
    #pragma unroll
    for (int j = 0; j < AJ; ++j) {
        int d = w * (AJ * 1024) + j * 1024 + lane * 16;
        int r = d >> 6;
        int c = ((d >> 4) & 3) ^ ((r >> 1) & 3);
        a_r[j] = r; a_c[j] = c * 8;
        a_dst[j] = (w * (AJ * 1024) + j * 1024) >> 1;  // element idx, wave-uniform
    }
    int b_r[2], b_c[2], b_dst[2];
    #pragma unroll
    for (int j = 0; j < 2; ++j) {
        int d = w * 2048 + j * 1024 + lane * 16;
        int r = d >> 6;
        int c = ((d >> 4) & 3) ^ ((r >> 1) & 3);
        b_r[j] = r; b_c[j] = c * 8;
        b_dst[j] = (w * 2048 + j * 1024) >> 1;
    }

    const unsigned short* Aptr = A  + (size_t)(bm * BM) * K;
    const unsigned short* Bptr = WT + (size_t)(bn * 128) * K;

    f32x4 acc[MF][4];
    #pragma unroll
    for (int m = 0; m < MF; ++m)
        #pragma unroll
        for (int n = 0; n < 4; ++n)
            acc[m][n] = (f32x4){0.f, 0.f, 0.f, 0.f};

    for (int kt = 0; kt < K; kt += 32) {
        __syncthreads();   // WAR: previous tile fully consumed
        #pragma unroll
        for (int j = 0; j < AJ; ++j) {
            const unsigned short* ga = Aptr + (size_t)a_r[j] * K + kt + a_c[j];
            __builtin_amdgcn_global_load_lds((const u32_g*)ga,
                                             (u32_l*)(As + a_dst[j]), 16, 0, 0);
        }
        #pragma unroll
        for (int j = 0; j < 2; ++j) {
            const unsigned short* gb = Bptr + (size_t)b_r[j] * K + kt + b_c[j];
            __builtin_amdgcn_global_load_lds((const u32_g*)gb,
                                             (u32_l*)(Bs + b_dst[j]), 16, 0, 0);
        }
        __syncthreads();   // compiler drains vmcnt(0) before barrier -> tile ready
        s16x8 af[MF], bfr[4];
        #pragma unroll
        for (int m = 0; m < MF; ++m) af[m] = *(const s16x8*)(As + aoff[m]);
        #pragma unroll
        for (int n = 0; n < 4; ++n) bfr[n] = *(const s16x8*)(Bs + boff[n]);
        #pragma unroll
        for (int m = 0; m < MF; ++m)
            #pragma unroll
            for (int n = 0; n < 4; ++n)
                acc[m][n] = __builtin_amdgcn_mfma_f32_16x16x32_bf16(
                    af[m], bfr[n], acc[m][n], 0, 0, 0);
    }

    // epilogue: C/D layout col=lane&15, row=(lane>>4)*4+reg  [m89-verified]
    const int orow0 = bm * BM + wm * (BM / 2);
    const int ocol0 = bn * 128 + wn * 64;
    const int rr = (lane >> 4) * 4;
    #pragma unroll
    for (int n = 0; n < 4; ++n) {
        int col = ocol0 + n * 16 + lr;
        float bv = bias[col];
        #pragma unroll
        for (int m = 0; m < MF; ++m) {
            #pragma unroll
            for (int q = 0; q < 4; ++q) {
                int row = orow0 + m * 16 + rr + q;
                float v = acc[m][n][q] + bv;
                if constexpr (RES) v += res[(size_t)row * ldo + col];
                if constexpr (RELU) v = fmaxf(v, 0.f);
                if constexpr (OUTBF)
                    ((unsigned short*)outp)[(size_t)row * ldo + col] = f2bf(v);
                else
                    ((float*)outp)[(size_t)row * ldo + col] = v;
            }
        }
    }
}

// ---------------------------------------------------------------------------
// Fused causal attention, fp32 compute, bf16 in (qkv) / bf16 out (y).
// Grid (T/32, H, B), 256 threads. qkv row = [q(H,D)|k(H,D)|v(H,D)], stride 3C.
// ---------------------------------------------------------------------------
__global__ __launch_bounds__(256)
void attn_kernel(const unsigned short* __restrict__ qkv,
                 unsigned short* __restrict__ y) {
    int qt = blockIdx.x, h = blockIdx.y, b = blockIdx.z;
    __shared__ float Qs[32][68], Ks[32][68], Vs[32][68];
    __shared__ float Ps[32][32];
    int tid = threadIdx.x;
    const unsigned short* qbase = qkv + (size_t)b * T * 3072 + h * 64;
    const unsigned short* kbase = qbase + 1024;
    const unsigned short* vbase = qbase + 2048;

    int lr_ = tid >> 3, ld8 = (tid & 7) * 8;
    {
        uint4 raw = *(const uint4*)(qbase + (size_t)(qt * 32 + lr_) * 3072 + ld8);
        const unsigned short* u = (const unsigned short*)&raw;
        #pragma unroll
        for (int i = 0; i < 8; ++i) Qs[lr_][ld8 + i] = bf2f(u[i]);
    }

    int rq = tid >> 3, g8 = tid & 7, sq = g8 * 4, d0 = g8 * 8;
    float O[8] = {0, 0, 0, 0, 0, 0, 0, 0};
    float m = -INFINITY, l = 0.f;
    const float scale = 0.125f;

    for (int st = 0; st <= qt; ++st) {
        __syncthreads();
        {
            uint4 kr = *(const uint4*)(kbase + (size_t)(st * 32 + lr_) * 3072 + ld8);
            uint4 vr = *(const uint4*)(vbase + (size_t)(st * 32 + lr_) * 3072 + ld8);
            const unsigned short* ku = (const unsigned short*)&kr;
            const unsigned short* vu = (const unsigned short*)&vr;
            #pragma unroll
            for (int i = 0; i < 8; ++i) {
                Ks[lr_][ld8 + i] = bf2f(ku[i]);
                Vs[lr_][ld8 + i] = bf2f(vu[i]);
            }
        }
        __syncthreads();

        float sc[4] = {0, 0, 0, 0};
        #pragma unroll
        for (int dd = 0; dd < DHEAD; dd += 4) {
            float4 qv = *(const float4*)&Qs[rq][dd];
            #pragma unroll
            for (int j = 0; j < 4; ++j) {
                float4 kv = *(const float4*)&Ks[sq + j][dd];
                sc[j] += qv.x * kv.x + qv.y * kv.y + qv.z * kv.z + qv.w * kv.w;
            }
        }
        int qglob = qt * 32 + rq;
        #pragma unroll
        for (int j = 0; j < 4; ++j) {
            int sglob = st * 32 + sq + j;
            sc[j] = (sglob <= qglob) ? sc[j] * scale : -INFINITY;
        }
        float tmax = fmaxf(fmaxf(sc[0], sc[1]), fmaxf(sc[2], sc[3]));
        #pragma unroll
        for (int off = 1; off < 8; off <<= 1)
            tmax = fmaxf(tmax, __shfl_xor(tmax, off, 8));
        float mnew = fmaxf(m, tmax);
        float alpha = expf(m - mnew);
        float p[4];
        float psum = 0.f;
        #pragma unroll
        for (int j = 0; j < 4; ++j) { p[j] = expf(sc[j] - mnew); psum += p[j]; }
        #pragma unroll
        for (int off = 1; off < 8; off <<= 1)
            psum += __shfl_xor(psum, off, 8);
        l = l * alpha + psum;
        m = mnew;
        #pragma unroll
        for (int j = 0; j < 8; ++j) O[j] *= alpha;
        *(float4*)&Ps[rq][sq] = make_float4(p[0], p[1], p[2], p[3]);
        __syncthreads();

        #pragma unroll 4
        for (int s = 0; s < 32; ++s) {
            float pv = Ps[rq][s];
            float4 v0 = *(const float4*)&Vs[s][d0];
            float4 v1 = *(const float4*)&Vs[s][d0 + 4];
            O[0] += pv * v0.x; O[1] += pv * v0.y; O[2] += pv * v0.z; O[3] += pv * v0.w;
            O[4] += pv * v1.x; O[5] += pv * v1.y; O[6] += pv * v1.z; O[7] += pv * v1.w;
        }
    }
    float inv = 1.f / l;
    unsigned short o8[8];
    #pragma unroll
    for (int j = 0; j < 8; ++j) o8[j] = f2bf(O[j] * inv);
    *(uint4*)(y + ((size_t)b * T + qt * 32 + rq) * CDIM + h * 64 + d0) = *(uint4*)o8;
}

// ---------------------------------------------------------------------------
extern "C" void kernel_launch(void* const* d_in, const int* in_sizes, int n_in,
                              void* d_out, int out_size, void* d_ws, size_t ws_size,
                              hipStream_t stream) {
    const int*   idx     = (const int*)d_in[0];
    const float* tok_emb = (const float*)d_in[1];
    const float* pos_emb = (const float*)d_in[2];
    const float* Wqkv    = (const float*)d_in[3];
    const float* bqkv    = (const float*)d_in[4];
    const float* Wproj   = (const float*)d_in[5];
    const float* bproj   = (const float*)d_in[6];
    const float* ln1_g   = (const float*)d_in[7];
    const float* ln1_b   = (const float*)d_in[8];
    const float* ln2_g   = (const float*)d_in[9];
    const float* ln2_b   = (const float*)d_in[10];
    const float* Wf1     = (const float*)d_in[11];
    const float* bf1     = (const float*)d_in[12];
    const float* Wf2     = (const float*)d_in[13];
    const float* bf2     = (const float*)d_in[14];
    const float* lnf_g   = (const float*)d_in[15];
    const float* lnf_b   = (const float*)d_in[16];
    const float* Whead   = (const float*)d_in[17];
    const float* bhead   = (const float*)d_in[18];
    float* out = (float*)d_out;

    const size_t MB = 1u << 20;
    char* base = (char*)d_ws;
    // layout: x fp32 8MB | h bf16 4MB | qkv 12MB + y 4MB (f 16MB aliases) | WT 24MB
    float*          x    = (float*)base;                          // [0,8M)
    unsigned short* h    = (unsigned short*)(base + 8 * MB);      // [8,12M)
    unsigned short* qkv  = (unsigned short*)(base + 12 * MB);     // [12,24M)
    unsigned short* y    = (unsigned short*)(base + 24 * MB);     // [24,28M)
    unsigned short* f    = (unsigned short*)(base + 12 * MB);     // [12,28M) alias
    unsigned short* wtq  = (unsigned short*)(base + 28 * MB);     // 6MB
    unsigned short* wtp  = (unsigned short*)(base + 34 * MB);     // 2MB
    unsigned short* wt1  = (unsigned short*)(base + 36 * MB);     // 8MB
    unsigned short* wt2  = (unsigned short*)(base + 44 * MB);     // 8MB  (end 52MB)
    unsigned short* wth  = (unsigned short*)(base + 28 * MB);     // 12.8MB head chunk

    const int MROWS = BATCH * T;  // 2048

    embed_kernel<<<MROWS, 256, 0, stream>>>(idx, tok_emb, pos_emb, x);

    for (int l = 0; l < NLAYER; ++l) {
        transpose_cvt<<<dim3(48, 16), 256, 0, stream>>>(
            Wqkv + (size_t)l * CDIM * 3 * CDIM, 3 * CDIM, wtq, CDIM);
        transpose_cvt<<<dim3(16, 16), 256, 0, stream>>>(
            Wproj + (size_t)l * CDIM * CDIM, CDIM, wtp, CDIM);
        transpose_cvt<<<dim3(64, 16), 256, 0, stream>>>(
            Wf1 + (size_t)l * CDIM * 4 * CDIM, 4 * CDIM, wt1, CDIM);
        transpose_cvt<<<dim3(16, 64), 256, 0, stream>>>(
            Wf2 + (size_t)l * 4 * CDIM * CDIM, CDIM, wt2, 4 * CDIM);

        ln_kernel<<<MROWS, 256, 0, stream>>>(x, ln1_g + (size_t)l * CDIM,
                                             ln1_b + (size_t)l * CDIM, h);
        // qkv = h @ Wqkv + bqkv   (bf16 out)  grid 24*16
        mfma_gemm<4, 4, true, false, false><<<24 * 16, 256, 0, stream>>>(
            h, wtq, bqkv + (size_t)l * 3 * CDIM, nullptr, qkv, CDIM, 3 * CDIM);
        attn_kernel<<<dim3(T / 32, NHEAD, BATCH), 256, 0, stream>>>(qkv, y);
        // x += y @ Wproj + bproj  (fp32, 64x128 tiles -> 256 blocks)
        mfma_gemm<2, 5, false, true, false><<<8 * 32, 256, 0, stream>>>(
            y, wtp, bproj + (size_t)l * CDIM, x, x, CDIM, CDIM);
        ln_kernel<<<MROWS, 256, 0, stream>>>(x, ln2_g + (size_t)l * CDIM,
                                             ln2_b + (size_t)l * CDIM, h);
        // f = relu(h @ Wf1 + bf1) (bf16 out) grid 32*16
        mfma_gemm<4, 4, true, false, true><<<32 * 16, 256, 0, stream>>>(
            h, wt1, bf1 + (size_t)l * 4 * CDIM, nullptr, f, CDIM, 4 * CDIM);
        // x += f @ Wf2 + bf2
        mfma_gemm<2, 5, false, true, false><<<8 * 32, 256, 0, stream>>>(
            f, wt2, bf2 + (size_t)l * CDIM, x, x, 4 * CDIM, CDIM);
    }

    ln_kernel<<<MROWS, 256, 0, stream>>>(x, lnf_g, lnf_b, h);
    // head in 5 N-chunks of 6400 (= 50 * 128), WT region reused
    for (int c = 0; c < 5; ++c) {
        transpose_cvt<<<dim3(100, 16), 256, 0, stream>>>(
            Whead + (size_t)c * 6400, VOCAB, wth, CDIM);
        mfma_gemm<4, 4, false, false, false><<<50 * 16, 256, 0, stream>>>(
            h, wth, bhead + (size_t)c * 6400, nullptr, out + (size_t)c * 6400,
            CDIM, VOCAB);
    }
}